// Round 1
// baseline (361.802 us; speedup 1.0000x reference)
//
#include <hip/hip_runtime.h>
#include <cstddef>

#define B_  2
#define N_  2048
#define L_  5
#define HH  8
#define P_  4
#define S_  21824
#define DQK 32

// ---------------------------------------------------------------------------
// Generic f32 GEMM: C = A[M,K] @ W[N,K]^T + bias[N]
// MODE 0: C row-major [M,N]
// MODE 1: kv transposed store: row m=(b,s), col j=(h,c) ->
//         C[((b*HH+h)*S_ + s)*64 + c]   (i.e. [B*HH, S, 64] layout)
// Tiles: BM=BN=64, BK=32, 256 threads, 4x4 micro-tile per thread.
// LDS is stored k-major (As[k][row]) so fragments are ds_read_b128.
// ---------------------------------------------------------------------------
template <int MODE>
__global__ __launch_bounds__(256) void gemm_f32(
    const float* __restrict__ A, const float* __restrict__ W,
    const float* __restrict__ bias, float* __restrict__ C,
    int M, int N, int K) {
  __shared__ float As[32][68];   // pad 68 floats: 272B row stride (16B aligned)
  __shared__ float Ws[32][68];

  const int tid = threadIdx.x;
  const int tx = tid & 15, ty = tid >> 4;
  const int row0 = blockIdx.y * 64, col0 = blockIdx.x * 64;
  const int r = tid >> 3;              // 0..31
  const int kq = (tid & 7) << 2;       // 0..28 step 4

  float acc[4][4] = {};

  for (int k0 = 0; k0 < K; k0 += 32) {
    const float4 a0 = *(const float4*)(A + (size_t)(row0 + r) * K + k0 + kq);
    const float4 a1 = *(const float4*)(A + (size_t)(row0 + r + 32) * K + k0 + kq);
    const float4 w0 = *(const float4*)(W + (size_t)(col0 + r) * K + k0 + kq);
    const float4 w1 = *(const float4*)(W + (size_t)(col0 + r + 32) * K + k0 + kq);
    __syncthreads();   // previous iteration's compute done before overwrite
    As[kq + 0][r] = a0.x; As[kq + 1][r] = a0.y; As[kq + 2][r] = a0.z; As[kq + 3][r] = a0.w;
    As[kq + 0][r + 32] = a1.x; As[kq + 1][r + 32] = a1.y; As[kq + 2][r + 32] = a1.z; As[kq + 3][r + 32] = a1.w;
    Ws[kq + 0][r] = w0.x; Ws[kq + 1][r] = w0.y; Ws[kq + 2][r] = w0.z; Ws[kq + 3][r] = w0.w;
    Ws[kq + 0][r + 32] = w1.x; Ws[kq + 1][r + 32] = w1.y; Ws[kq + 2][r + 32] = w1.z; Ws[kq + 3][r + 32] = w1.w;
    __syncthreads();
#pragma unroll
    for (int kk = 0; kk < 32; ++kk) {
      const float4 av = *(const float4*)&As[kk][ty << 2];
      const float4 bv = *(const float4*)&Ws[kk][tx << 2];
      const float* ap = (const float*)&av;
      const float* bp = (const float*)&bv;
#pragma unroll
      for (int i = 0; i < 4; ++i)
#pragma unroll
        for (int j = 0; j < 4; ++j) acc[i][j] += ap[i] * bp[j];
    }
  }

  const float4 bb = *(const float4*)(bias + col0 + (tx << 2));
  const float* bbp = (const float*)&bb;
#pragma unroll
  for (int i = 0; i < 4; ++i) {
    const int m = row0 + (ty << 2) + i;
    float4 o;
    o.x = acc[i][0] + bbp[0];
    o.y = acc[i][1] + bbp[1];
    o.z = acc[i][2] + bbp[2];
    o.w = acc[i][3] + bbp[3];
    if (MODE == 0) {
      *(float4*)(C + (size_t)m * N + col0 + (tx << 2)) = o;
    } else {
      const int b = m / S_;
      const int s = m - b * S_;
      const int jb = col0 + (tx << 2);
      const int h = jb >> 6, c = jb & 63;
      *(float4*)(C + ((size_t)(b * HH + h) * S_ + s) * 64 + c) = o;
    }
  }
}

// ---------------------------------------------------------------------------
// Bilinear sampling + 20-point attention. One 64-lane wave per (b, n, h);
// 4 waves per 256-thread block. Lane = channel (0..63) of the per-head kv.
// Channels 0..31 = key, 32..63 = value. Softmax held entirely in registers
// (full 64-lane shfl_xor reduction broadcasts each logit to all lanes).
// ---------------------------------------------------------------------------
__global__ __launch_bounds__(256) void sample_attn(
    const float* __restrict__ kvt,      // [B*HH, S, 64]
    const float* __restrict__ offb,     // [B*N, 320]
    const float* __restrict__ qb,       // [B*N, 256]
    const float* __restrict__ priors,   // [B, N, L, 2]
    const int* __restrict__ shapes,     // [L, 2]  (H, W)
    const int* __restrict__ starts,     // [L]
    const float* __restrict__ pencs,    // [HH, 20, 32]
    float* __restrict__ weighted) {     // [B*N, 256]
  const int grp = blockIdx.x * 4 + (threadIdx.x >> 6);  // (b*N + n)*HH + h
  const int lane = threadIdx.x & 63;
  const int h = grp & (HH - 1);
  const int bn = grp >> 3;
  const int b = bn >> 11;  // / N_

  const float* kvbase = kvt + (size_t)(b * HH + h) * S_ * 64 + lane;

  float q = 0.f;
  if (lane < DQK) q = qb[(size_t)bn * 256 + h * DQK + lane] * 0.17677669529663687f;

  float sampled[L_ * P_];
  float logits[L_ * P_];

#pragma unroll
  for (int l = 0; l < L_; ++l) {
    const int Wd = shapes[l * 2 + 1];
    const int Hd = shapes[l * 2 + 0];
    const float Wf = (float)Wd, Hf = (float)Hd;
    const int st = starts[l];
    const float px = priors[((size_t)bn * L_ + l) * 2 + 0];
    const float py = priors[((size_t)bn * L_ + l) * 2 + 1];
#pragma unroll
    for (int p = 0; p < P_; ++p) {
      const int pp = l * P_ + p;
      const float ox = offb[(size_t)bn * 320 + h * 40 + l * 8 + p * 2 + 0];
      const float oy = offb[(size_t)bn * 320 + h * 40 + l * 8 + p * 2 + 1];
      const float lx = px + ox / Wf;
      const float ly = py + oy / Hf;
      const float x = lx * Wf - 0.5f;
      const float y = ly * Hf - 0.5f;
      const float x0 = floorf(x), y0 = floorf(y);
      const float fx = x - x0, fy = y - y0;
      const int xi = (int)x0, yi = (int)y0;

      float val = 0.f;
#pragma unroll
      for (int dy = 0; dy < 2; ++dy) {
#pragma unroll
        for (int dx = 0; dx < 2; ++dx) {
          const float wgt = (dx ? fx : 1.f - fx) * (dy ? fy : 1.f - fy);
          const int xc = xi + dx, yc = yi + dy;
          const bool valid = (xc >= 0) & (xc < Wd) & (yc >= 0) & (yc < Hd);
          const int xcc = min(max(xc, 0), Wd - 1);
          const int ycc = min(max(yc, 0), Hd - 1);
          const float f = kvbase[(size_t)(st + ycc * Wd + xcc) * 64];
          val += valid ? wgt * f : 0.f;
        }
      }
      sampled[pp] = val;

      float part = 0.f;
      if (lane < DQK) part = q * (val + pencs[(h * 20 + pp) * DQK + lane]);
#pragma unroll
      for (int m = 32; m >= 1; m >>= 1) part += __shfl_xor(part, m, 64);
      logits[pp] = part;   // identical on all 64 lanes
    }
  }

  float mx = logits[0];
#pragma unroll
  for (int pp = 1; pp < L_ * P_; ++pp) mx = fmaxf(mx, logits[pp]);
  float se = 0.f;
#pragma unroll
  for (int pp = 0; pp < L_ * P_; ++pp) {
    logits[pp] = __expf(logits[pp] - mx);
    se += logits[pp];
  }
  const float inv = 1.f / se;

  if (lane >= 32) {
    float acc = 0.f;
#pragma unroll
    for (int pp = 0; pp < L_ * P_; ++pp) acc += logits[pp] * inv * sampled[pp];
    weighted[(size_t)bn * 256 + h * DQK + (lane - 32)] = acc;
  }
}

// ---------------------------------------------------------------------------
extern "C" void kernel_launch(void* const* d_in, const int* in_sizes, int n_in,
                              void* d_out, int out_size, void* d_ws, size_t ws_size,
                              hipStream_t stream) {
  const float* in_feats = (const float*)d_in[0];
  const float* priors   = (const float*)d_in[1];
  const float* sfeats   = (const float*)d_in[2];
  const int*   shapes   = (const int*)d_in[3];
  const int*   starts   = (const int*)d_in[4];
  const float* W_off    = (const float*)d_in[5];
  const float* b_off    = (const float*)d_in[6];
  const float* W_q      = (const float*)d_in[7];
  const float* b_q      = (const float*)d_in[8];
  const float* W_kv     = (const float*)d_in[9];
  const float* b_kv     = (const float*)d_in[10];
  const float* pencs    = (const float*)d_in[11];
  const float* W_out    = (const float*)d_in[12];
  const float* b_out    = (const float*)d_in[13];
  float* out = (float*)d_out;

  float* ws   = (float*)d_ws;
  float* kvt  = ws;                                   // B*HH*S*64 = 22,347,776
  float* offb = kvt + (size_t)B_ * HH * S_ * 64;      // B*N*320  =  1,310,720
  float* qb   = offb + (size_t)B_ * N_ * 320;         // B*N*256  =  1,048,576
  float* wtd  = qb + (size_t)B_ * N_ * 256;           // B*N*256  =  1,048,576

  const int MBN = B_ * N_;   // 4096
  const int MKV = B_ * S_;   // 43648

  // kv = sample_feats @ W_kv^T + b_kv, stored as [B*HH, S, 64]
  gemm_f32<1><<<dim3(512 / 64, MKV / 64), 256, 0, stream>>>(
      sfeats, W_kv, b_kv, kvt, MKV, 512, 256);
  // off = in_feats @ W_off^T + b_off   [4096, 320]
  gemm_f32<0><<<dim3(320 / 64, MBN / 64), 256, 0, stream>>>(
      in_feats, W_off, b_off, offb, MBN, 320, 256);
  // q = in_feats @ W_q^T + b_q         [4096, 256]
  gemm_f32<0><<<dim3(256 / 64, MBN / 64), 256, 0, stream>>>(
      in_feats, W_q, b_q, qb, MBN, 256, 256);
  // bilinear sample + attention -> weighted [4096, 256]
  sample_attn<<<(B_ * N_ * HH) / 4, 256, 0, stream>>>(
      kvt, offb, qb, priors, shapes, starts, pencs, wtd);
  // out = weighted @ W_out^T + b_out   [4096, 256]
  gemm_f32<0><<<dim3(256 / 64, MBN / 64), 256, 0, stream>>>(
      wtd, W_out, b_out, out, MBN, 256, 256);
}

// Round 3
// 222.859 us; speedup vs baseline: 1.6235x; 1.6235x over previous
//
#include <hip/hip_runtime.h>
#include <cstddef>

#define B_  2
#define N_  2048
#define L_  5
#define HH  8
#define P_  4
#define S_  21824
#define DQK 32

using bf16x8 = __attribute__((ext_vector_type(8))) short;
using f32x4  = __attribute__((ext_vector_type(4))) float;
using us8    = __attribute__((ext_vector_type(8))) unsigned short;

__device__ __forceinline__ unsigned short f2b(float f) {
  unsigned u = __builtin_bit_cast(unsigned, f);
  u += 0x7FFFu + ((u >> 16) & 1u);            // round-to-nearest-even
  return (unsigned short)(u >> 16);
}
__device__ __forceinline__ float b2f(unsigned short h) {
  return __builtin_bit_cast(float, ((unsigned)h) << 16);
}

__device__ __forceinline__ void gld_lds16(const void* g, void* l) {
  __builtin_amdgcn_global_load_lds(
      (const __attribute__((address_space(1))) unsigned int*)g,
      (__attribute__((address_space(3))) unsigned int*)l, 16, 0, 0);
}

// ---------------------------------------------------------------------------
// f32 -> bf16 conversion, 8 elems/thread
// ---------------------------------------------------------------------------
__global__ __launch_bounds__(256) void cvt_f32_bf16(
    const float* __restrict__ in, unsigned short* __restrict__ out, int n8) {
  const int i = blockIdx.x * 256 + threadIdx.x;
  if (i >= n8) return;
  const float4 a = ((const float4*)in)[2 * i];
  const float4 b = ((const float4*)in)[2 * i + 1];
  us8 o;
  o[0] = f2b(a.x); o[1] = f2b(a.y); o[2] = f2b(a.z); o[3] = f2b(a.w);
  o[4] = f2b(b.x); o[5] = f2b(b.y); o[6] = f2b(b.z); o[7] = f2b(b.w);
  ((us8*)out)[i] = o;
}

// ---------------------------------------------------------------------------
// kv GEMM: C[M=43648, N=512] = A[M,256] @ W[512,256]^T + bias, stored bf16 as
// kvt[(b*HH+h)*S_ + s][c]  (m=(b,s), n=(h,c)).
// 128x128 tile, BK=64, 256 threads = 4 waves (2x2), mfma_f32_16x16x32_bf16.
// LDS staged via global_load_lds(16B) with XOR chunk swizzle applied on the
// GLOBAL source address (LDS dest stays linear) and on ds_read (rule 21).
// ---------------------------------------------------------------------------
__global__ __launch_bounds__(256) void gemm_kv_mfma(
    const unsigned short* __restrict__ A,   // [43648,256] bf16
    const unsigned short* __restrict__ Wt,  // [512,256] bf16
    const float* __restrict__ bias,         // [512]
    unsigned short* __restrict__ kvt) {     // [16, S_, 64] bf16
  __shared__ __align__(16) unsigned short As[128 * 64];
  __shared__ __align__(16) unsigned short Bs[128 * 64];

  const int tid = threadIdx.x;
  const int lane = tid & 63;
  const int wv = tid >> 6;
  const int wr = wv >> 1, wc = wv & 1;
  const int fr = lane & 15, fq = lane >> 4;
  const int row0 = blockIdx.y * 128, col0 = blockIdx.x * 128;
  const int srow = tid >> 3;   // 0..31
  const int sch = tid & 7;     // 16B chunk within a 128B row

  f32x4 acc[4][4] = {};

  for (int k0 = 0; k0 < 256; k0 += 64) {
#pragma unroll
    for (int i = 0; i < 4; ++i) {
      const int r = i * 32 + srow;
      const int ca = sch ^ (r & 7);    // pre-swizzled source chunk
      gld_lds16(A + (size_t)(row0 + r) * 256 + k0 + ca * 8,
                As + (size_t)(i * 32 + wv * 8) * 64);
      gld_lds16(Wt + (size_t)(col0 + r) * 256 + k0 + ca * 8,
                Bs + (size_t)(i * 32 + wv * 8) * 64);
    }
    __syncthreads();   // drains vmcnt: staged tile visible
#pragma unroll
    for (int kk = 0; kk < 2; ++kk) {
      bf16x8 af[4], bfv[4];
#pragma unroll
      for (int i = 0; i < 4; ++i) {
        const int ar = wr * 64 + i * 16 + fr;
        const int cha = (kk * 4 + fq) ^ (ar & 7);
        af[i] = *(const bf16x8*)(As + ar * 64 + cha * 8);
        const int br = wc * 64 + i * 16 + fr;
        const int chb = (kk * 4 + fq) ^ (br & 7);
        bfv[i] = *(const bf16x8*)(Bs + br * 64 + chb * 8);
      }
#pragma unroll
      for (int i = 0; i < 4; ++i)
#pragma unroll
        for (int j = 0; j < 4; ++j)
          acc[i][j] = __builtin_amdgcn_mfma_f32_16x16x32_bf16(
              af[i], bfv[j], acc[i][j], 0, 0, 0);
    }
    __syncthreads();   // compute done before next stage overwrites
  }

#pragma unroll
  for (int j = 0; j < 4; ++j) {
    const int n = col0 + wc * 64 + j * 16 + fr;
    const float bv = bias[n];
    const int h = n >> 6, c = n & 63;
#pragma unroll
    for (int i = 0; i < 4; ++i) {
      const int mbase = row0 + wr * 64 + i * 16 + fq * 4;
#pragma unroll
      for (int r = 0; r < 4; ++r) {
        const int m = mbase + r;
        const int b = (m >= S_) ? 1 : 0;
        const int s = m - b * S_;
        kvt[((size_t)(b * HH + h) * S_ + s) * 64 + c] = f2b(acc[i][j][r] + bv);
      }
    }
  }
}

// ---------------------------------------------------------------------------
// f32 GEMM (kept for off/q/out): C = A[M,K] @ W[N,K]^T + bias, row-major C
// ---------------------------------------------------------------------------
__global__ __launch_bounds__(256) void gemm_f32(
    const float* __restrict__ A, const float* __restrict__ W,
    const float* __restrict__ bias, float* __restrict__ C,
    int M, int N, int K) {
  __shared__ float Asm[32][68];
  __shared__ float Wsm[32][68];

  const int tid = threadIdx.x;
  const int tx = tid & 15, ty = tid >> 4;
  const int row0 = blockIdx.y * 64, col0 = blockIdx.x * 64;
  const int r = tid >> 3;
  const int kq = (tid & 7) << 2;

  float acc[4][4] = {};

  for (int k0 = 0; k0 < K; k0 += 32) {
    const float4 a0 = *(const float4*)(A + (size_t)(row0 + r) * K + k0 + kq);
    const float4 a1 = *(const float4*)(A + (size_t)(row0 + r + 32) * K + k0 + kq);
    const float4 w0 = *(const float4*)(W + (size_t)(col0 + r) * K + k0 + kq);
    const float4 w1 = *(const float4*)(W + (size_t)(col0 + r + 32) * K + k0 + kq);
    __syncthreads();
    Asm[kq + 0][r] = a0.x; Asm[kq + 1][r] = a0.y; Asm[kq + 2][r] = a0.z; Asm[kq + 3][r] = a0.w;
    Asm[kq + 0][r + 32] = a1.x; Asm[kq + 1][r + 32] = a1.y; Asm[kq + 2][r + 32] = a1.z; Asm[kq + 3][r + 32] = a1.w;
    Wsm[kq + 0][r] = w0.x; Wsm[kq + 1][r] = w0.y; Wsm[kq + 2][r] = w0.z; Wsm[kq + 3][r] = w0.w;
    Wsm[kq + 0][r + 32] = w1.x; Wsm[kq + 1][r + 32] = w1.y; Wsm[kq + 2][r + 32] = w1.z; Wsm[kq + 3][r + 32] = w1.w;
    __syncthreads();
#pragma unroll
    for (int kk = 0; kk < 32; ++kk) {
      const float4 av = *(const float4*)&Asm[kk][ty << 2];
      const float4 bv = *(const float4*)&Wsm[kk][tx << 2];
      const float* ap = (const float*)&av;
      const float* bp = (const float*)&bv;
#pragma unroll
      for (int i = 0; i < 4; ++i)
#pragma unroll
        for (int j = 0; j < 4; ++j) acc[i][j] += ap[i] * bp[j];
    }
  }

  const float4 bb = *(const float4*)(bias + col0 + (tx << 2));
  const float* bbp = (const float*)&bb;
#pragma unroll
  for (int i = 0; i < 4; ++i) {
    const int m = row0 + (ty << 2) + i;
    float4 o;
    o.x = acc[i][0] + bbp[0];
    o.y = acc[i][1] + bbp[1];
    o.z = acc[i][2] + bbp[2];
    o.w = acc[i][3] + bbp[3];
    *(float4*)(C + (size_t)m * N + col0 + (tx << 2)) = o;
  }
}

// ---------------------------------------------------------------------------
// Bilinear sampling + 20-point attention, one wave per (b,n,h), lane=channel.
// kv is bf16 now (halves gather traffic).
// ---------------------------------------------------------------------------
__global__ __launch_bounds__(256) void sample_attn(
    const unsigned short* __restrict__ kvt, // [B*HH, S, 64] bf16
    const float* __restrict__ offb,         // [B*N, 320]
    const float* __restrict__ qb,           // [B*N, 256]
    const float* __restrict__ priors,       // [B, N, L, 2]
    const int* __restrict__ shapes,         // [L, 2]  (H, W)
    const int* __restrict__ starts,         // [L]
    const float* __restrict__ pencs,        // [HH, 20, 32]
    float* __restrict__ weighted) {         // [B*N, 256]
  const int grp = blockIdx.x * 4 + (threadIdx.x >> 6);
  const int lane = threadIdx.x & 63;
  const int h = grp & (HH - 1);
  const int bn = grp >> 3;
  const int b = bn >> 11;

  const unsigned short* kvbase = kvt + (size_t)(b * HH + h) * S_ * 64 + lane;

  float q = 0.f;
  if (lane < DQK) q = qb[(size_t)bn * 256 + h * DQK + lane] * 0.17677669529663687f;

  float sampled[L_ * P_];
  float logits[L_ * P_];

#pragma unroll
  for (int l = 0; l < L_; ++l) {
    const int Wd = shapes[l * 2 + 1];
    const int Hd = shapes[l * 2 + 0];
    const float Wf = (float)Wd, Hf = (float)Hd;
    const int st = starts[l];
    const float px = priors[((size_t)bn * L_ + l) * 2 + 0];
    const float py = priors[((size_t)bn * L_ + l) * 2 + 1];
#pragma unroll
    for (int p = 0; p < P_; ++p) {
      const int pp = l * P_ + p;
      const float ox = offb[(size_t)bn * 320 + h * 40 + l * 8 + p * 2 + 0];
      const float oy = offb[(size_t)bn * 320 + h * 40 + l * 8 + p * 2 + 1];
      const float x = (px + ox / Wf) * Wf - 0.5f;
      const float y = (py + oy / Hf) * Hf - 0.5f;
      const float x0 = floorf(x), y0 = floorf(y);
      const float fx = x - x0, fy = y - y0;
      const int xi = (int)x0, yi = (int)y0;

      float val = 0.f;
#pragma unroll
      for (int dy = 0; dy < 2; ++dy) {
#pragma unroll
        for (int dx = 0; dx < 2; ++dx) {
          const float wgt = (dx ? fx : 1.f - fx) * (dy ? fy : 1.f - fy);
          const int xc = xi + dx, yc = yi + dy;
          const bool valid = (xc >= 0) & (xc < Wd) & (yc >= 0) & (yc < Hd);
          const int xcc = min(max(xc, 0), Wd - 1);
          const int ycc = min(max(yc, 0), Hd - 1);
          const float f = b2f(kvbase[(size_t)(st + ycc * Wd + xcc) * 64]);
          val += valid ? wgt * f : 0.f;
        }
      }
      sampled[pp] = val;

      float part = 0.f;
      if (lane < DQK) part = q * (val + pencs[(h * 20 + pp) * DQK + lane]);
#pragma unroll
      for (int m = 32; m >= 1; m >>= 1) part += __shfl_xor(part, m, 64);
      logits[pp] = part;
    }
  }

  float mx = logits[0];
#pragma unroll
  for (int pp = 1; pp < L_ * P_; ++pp) mx = fmaxf(mx, logits[pp]);
  float se = 0.f;
#pragma unroll
  for (int pp = 0; pp < L_ * P_; ++pp) {
    logits[pp] = __expf(logits[pp] - mx);
    se += logits[pp];
  }
  const float inv = 1.f / se;

  if (lane >= 32) {
    float acc = 0.f;
#pragma unroll
    for (int pp = 0; pp < L_ * P_; ++pp) acc += logits[pp] * inv * sampled[pp];
    weighted[(size_t)bn * 256 + h * DQK + (lane - 32)] = acc;
  }
}

// ---------------------------------------------------------------------------
extern "C" void kernel_launch(void* const* d_in, const int* in_sizes, int n_in,
                              void* d_out, int out_size, void* d_ws, size_t ws_size,
                              hipStream_t stream) {
  const float* in_feats = (const float*)d_in[0];
  const float* priors   = (const float*)d_in[1];
  const float* sfeats   = (const float*)d_in[2];
  const int*   shapes   = (const int*)d_in[3];
  const int*   starts   = (const int*)d_in[4];
  const float* W_off    = (const float*)d_in[5];
  const float* b_off    = (const float*)d_in[6];
  const float* W_q      = (const float*)d_in[7];
  const float* b_q      = (const float*)d_in[8];
  const float* W_kv     = (const float*)d_in[9];
  const float* b_kv     = (const float*)d_in[10];
  const float* pencs    = (const float*)d_in[11];
  const float* W_out    = (const float*)d_in[12];
  const float* b_out    = (const float*)d_in[13];
  float* out = (float*)d_out;

  char* w = (char*)d_ws;
  unsigned short* kvt = (unsigned short*)w;            // 16*S_*64 bf16
  w += (size_t)B_ * HH * S_ * 64 * 2;
  unsigned short* A_bf = (unsigned short*)w;           // 43648*256 bf16
  w += (size_t)B_ * S_ * 256 * 2;
  unsigned short* Wkv_bf = (unsigned short*)w;         // 512*256 bf16
  w += (size_t)512 * 256 * 2;
  float* offb = (float*)w;  w += (size_t)B_ * N_ * 320 * 4;
  float* qb   = (float*)w;  w += (size_t)B_ * N_ * 256 * 4;
  float* wtd  = (float*)w;

  const int MBN = B_ * N_;  // 4096

  const int n8_sf = (B_ * S_ * 256) / 8;   // 1,396,736
  const int n8_wk = (512 * 256) / 8;       // 16,384
  cvt_f32_bf16<<<(n8_sf + 255) / 256, 256, 0, stream>>>(sfeats, A_bf, n8_sf);
  cvt_f32_bf16<<<(n8_wk + 255) / 256, 256, 0, stream>>>(W_kv, Wkv_bf, n8_wk);

  // kv = sfeats @ W_kv^T + b_kv  -> bf16 [B*HH, S, 64]
  gemm_kv_mfma<<<dim3(512 / 128, (B_ * S_) / 128), 256, 0, stream>>>(
      A_bf, Wkv_bf, b_kv, kvt);

  gemm_f32<<<dim3(320 / 64, MBN / 64), 256, 0, stream>>>(
      in_feats, W_off, b_off, offb, MBN, 320, 256);
  gemm_f32<<<dim3(256 / 64, MBN / 64), 256, 0, stream>>>(
      in_feats, W_q, b_q, qb, MBN, 256, 256);

  sample_attn<<<(B_ * N_ * HH) / 4, 256, 0, stream>>>(
      kvt, offb, qb, priors, shapes, starts, pencs, wtd);

  gemm_f32<<<dim3(256 / 64, MBN / 64), 256, 0, stream>>>(
      wtd, W_out, b_out, out, MBN, 256, 256);
}

// Round 5
// 139.865 us; speedup vs baseline: 2.5868x; 1.5934x over previous
//
#include <hip/hip_runtime.h>
#include <cstddef>

#define B_  2
#define N_  2048
#define L_  5
#define HH  8
#define P_  4
#define S_  21824
#define DQK 32

using bf16x8 = __attribute__((ext_vector_type(8))) short;
using f32x4  = __attribute__((ext_vector_type(4))) float;
using us8    = __attribute__((ext_vector_type(8))) unsigned short;

__device__ __forceinline__ unsigned short f2b(float f) {
  unsigned u = __builtin_bit_cast(unsigned, f);
  u += 0x7FFFu + ((u >> 16) & 1u);            // round-to-nearest-even
  return (unsigned short)(u >> 16);
}
__device__ __forceinline__ float b2f(unsigned short h) {
  return __builtin_bit_cast(float, ((unsigned)h) << 16);
}

__device__ __forceinline__ void gld_lds16(const void* g, void* l) {
  __builtin_amdgcn_global_load_lds(
      (const __attribute__((address_space(1))) unsigned int*)g,
      (__attribute__((address_space(3))) unsigned int*)l, 16, 0, 0);
}

// ---------------------------------------------------------------------------
// f32 -> bf16 conversion, 8 elems/thread
// ---------------------------------------------------------------------------
__global__ __launch_bounds__(256) void cvt_f32_bf16(
    const float* __restrict__ in, unsigned short* __restrict__ out, int n8) {
  const int i = blockIdx.x * 256 + threadIdx.x;
  if (i >= n8) return;
  const float4 a = ((const float4*)in)[2 * i];
  const float4 b = ((const float4*)in)[2 * i + 1];
  us8 o;
  o[0] = f2b(a.x); o[1] = f2b(a.y); o[2] = f2b(a.z); o[3] = f2b(a.w);
  o[4] = f2b(b.x); o[5] = f2b(b.y); o[6] = f2b(b.z); o[7] = f2b(b.w);
  ((us8*)out)[i] = o;
}

// ---------------------------------------------------------------------------
// bf16 MFMA GEMM: C[M,N] = A[M,K]bf16 @ W[N,K]bf16^T + bias_f32
// MODE 0: C = float*, row-major [M,N]
// MODE 1: C = ushort* (bf16), kv layout: m=(b,s), n=(h,c) ->
//         C[((b*HH+h)*S_ + s)*64 + c]
// 128x128 tile, BK=64, 4 waves (2x2). global_load_lds(16B) staging with XOR
// chunk swizzle on the GLOBAL source + swizzled ds_read (both-sides, rule 21).
// ---------------------------------------------------------------------------
template <int MODE>
__global__ __launch_bounds__(256) void gemm_mfma(
    const unsigned short* __restrict__ A,
    const unsigned short* __restrict__ Wt,
    const float* __restrict__ bias,
    void* __restrict__ Cv, int N, int K) {
  __shared__ __align__(16) unsigned short As[128 * 64];
  __shared__ __align__(16) unsigned short Bs[128 * 64];

  const int tid = threadIdx.x;
  const int lane = tid & 63;
  const int wv = tid >> 6;
  const int wr = wv >> 1, wc = wv & 1;
  const int fr = lane & 15, fq = lane >> 4;
  const int row0 = blockIdx.y * 128, col0 = blockIdx.x * 128;
  const int srow = tid >> 3;
  const int sch = tid & 7;

  f32x4 acc[4][4] = {};

  for (int k0 = 0; k0 < K; k0 += 64) {
#pragma unroll
    for (int i = 0; i < 4; ++i) {
      const int r = i * 32 + srow;
      const int ca = sch ^ (r & 7);
      gld_lds16(A + (size_t)(row0 + r) * K + k0 + ca * 8,
                As + (size_t)(i * 32 + wv * 8) * 64);
      gld_lds16(Wt + (size_t)(col0 + r) * K + k0 + ca * 8,
                Bs + (size_t)(i * 32 + wv * 8) * 64);
    }
    __syncthreads();
#pragma unroll
    for (int kk = 0; kk < 2; ++kk) {
      bf16x8 af[4], bfv[4];
#pragma unroll
      for (int i = 0; i < 4; ++i) {
        const int ar = wr * 64 + i * 16 + fr;
        const int cha = (kk * 4 + fq) ^ (ar & 7);
        af[i] = *(const bf16x8*)(As + ar * 64 + cha * 8);
        const int br = wc * 64 + i * 16 + fr;
        const int chb = (kk * 4 + fq) ^ (br & 7);
        bfv[i] = *(const bf16x8*)(Bs + br * 64 + chb * 8);
      }
#pragma unroll
      for (int i = 0; i < 4; ++i)
#pragma unroll
        for (int j = 0; j < 4; ++j)
          acc[i][j] = __builtin_amdgcn_mfma_f32_16x16x32_bf16(
              af[i], bfv[j], acc[i][j], 0, 0, 0);
    }
    __syncthreads();
  }

#pragma unroll
  for (int j = 0; j < 4; ++j) {
    const int n = col0 + wc * 64 + j * 16 + fr;
    const float bv = bias[n];
#pragma unroll
    for (int i = 0; i < 4; ++i) {
      const int mbase = row0 + wr * 64 + i * 16 + fq * 4;
#pragma unroll
      for (int r = 0; r < 4; ++r) {
        const int m = mbase + r;
        if (MODE == 0) {
          ((float*)Cv)[(size_t)m * N + n] = acc[i][j][r] + bv;
        } else {
          const int b = (m >= S_) ? 1 : 0;
          const int s = m - b * S_;
          const int h = n >> 6, c = n & 63;
          ((unsigned short*)Cv)[((size_t)(b * HH + h) * S_ + s) * 64 + c] =
              f2b(acc[i][j][r] + bv);
        }
      }
    }
  }
}

// ---------------------------------------------------------------------------
// f32 GEMM (kept for off: N=320): C = A[M,K] @ W[N,K]^T + bias, row-major
// ---------------------------------------------------------------------------
__global__ __launch_bounds__(256) void gemm_f32(
    const float* __restrict__ A, const float* __restrict__ W,
    const float* __restrict__ bias, float* __restrict__ C,
    int M, int N, int K) {
  __shared__ float Asm[32][68];
  __shared__ float Wsm[32][68];

  const int tid = threadIdx.x;
  const int tx = tid & 15, ty = tid >> 4;
  const int row0 = blockIdx.y * 64, col0 = blockIdx.x * 64;
  const int r = tid >> 3;
  const int kq = (tid & 7) << 2;

  float acc[4][4] = {};

  for (int k0 = 0; k0 < K; k0 += 32) {
    const float4 a0 = *(const float4*)(A + (size_t)(row0 + r) * K + k0 + kq);
    const float4 a1 = *(const float4*)(A + (size_t)(row0 + r + 32) * K + k0 + kq);
    const float4 w0 = *(const float4*)(W + (size_t)(col0 + r) * K + k0 + kq);
    const float4 w1 = *(const float4*)(W + (size_t)(col0 + r + 32) * K + k0 + kq);
    __syncthreads();
    Asm[kq + 0][r] = a0.x; Asm[kq + 1][r] = a0.y; Asm[kq + 2][r] = a0.z; Asm[kq + 3][r] = a0.w;
    Asm[kq + 0][r + 32] = a1.x; Asm[kq + 1][r + 32] = a1.y; Asm[kq + 2][r + 32] = a1.z; Asm[kq + 3][r + 32] = a1.w;
    Wsm[kq + 0][r] = w0.x; Wsm[kq + 1][r] = w0.y; Wsm[kq + 2][r] = w0.z; Wsm[kq + 3][r] = w0.w;
    Wsm[kq + 0][r + 32] = w1.x; Wsm[kq + 1][r + 32] = w1.y; Wsm[kq + 2][r + 32] = w1.z; Wsm[kq + 3][r + 32] = w1.w;
    __syncthreads();
#pragma unroll
    for (int kk = 0; kk < 32; ++kk) {
      const float4 av = *(const float4*)&Asm[kk][ty << 2];
      const float4 bv = *(const float4*)&Wsm[kk][tx << 2];
      const float* ap = (const float*)&av;
      const float* bp = (const float*)&bv;
#pragma unroll
      for (int i = 0; i < 4; ++i)
#pragma unroll
        for (int j = 0; j < 4; ++j) acc[i][j] += ap[i] * bp[j];
    }
  }

  const float4 bb = *(const float4*)(bias + col0 + (tx << 2));
  const float* bbp = (const float*)&bb;
#pragma unroll
  for (int i = 0; i < 4; ++i) {
    const int m = row0 + (ty << 2) + i;
    float4 o;
    o.x = acc[i][0] + bbp[0];
    o.y = acc[i][1] + bbp[1];
    o.z = acc[i][2] + bbp[2];
    o.w = acc[i][3] + bbp[3];
    *(float4*)(C + (size_t)m * N + col0 + (tx << 2)) = o;
  }
}

// ---------------------------------------------------------------------------
// prep_points: one LANE per (bn, h, l, p) point. Computes 4 clamped corner
// addresses + validity-masked bilinear weights. 8 dwords per point.
// ---------------------------------------------------------------------------
__global__ __launch_bounds__(256) void prep_points(
    const float* __restrict__ offb,     // [B*N, 320]
    const float* __restrict__ priors,   // [B, N, L, 2]
    const int* __restrict__ shapes,     // [L, 2] (H, W)
    const int* __restrict__ starts,     // [L]
    int* __restrict__ prep) {           // [B*N*HH*20, 8]
  const int t = blockIdx.x * 256 + threadIdx.x;   // grid sized exactly
  const int p = t & 3;
  const int l = (t >> 2) % 5;
  const int gh = t / 20;            // bn*8 + h
  const int hh = gh & 7;
  const int bn = t / 160;

  const float2 oxy = *(const float2*)(offb + (size_t)bn * 320 + hh * 40 + l * 8 + p * 2);
  const float2 pxy = *(const float2*)(priors + ((size_t)bn * 5 + l) * 2);
  const int Wd = shapes[l * 2 + 1];
  const int Hd = shapes[l * 2 + 0];
  const int st = starts[l];
  const float Wf = (float)Wd, Hf = (float)Hd;

  const float x = (pxy.x + oxy.x / Wf) * Wf - 0.5f;
  const float y = (pxy.y + oxy.y / Hf) * Hf - 0.5f;
  const float x0f = floorf(x), y0f = floorf(y);
  const float fx = x - x0f, fy = y - y0f;
  const int xi = (int)x0f, yi = (int)y0f;

  int a[4]; float w[4];
#pragma unroll
  for (int dy = 0; dy < 2; ++dy)
#pragma unroll
    for (int dx = 0; dx < 2; ++dx) {
      const int xc = xi + dx, yc = yi + dy;
      const bool valid = (xc >= 0) & (xc < Wd) & (yc >= 0) & (yc < Hd);
      const float wt = (dx ? fx : 1.f - fx) * (dy ? fy : 1.f - fy);
      const int xcc = min(max(xc, 0), Wd - 1);
      const int ycc = min(max(yc, 0), Hd - 1);
      a[dy * 2 + dx] = st + ycc * Wd + xcc;
      w[dy * 2 + dx] = valid ? wt : 0.f;
    }
  *(int4*)(prep + (size_t)t * 8) = make_int4(a[0], a[1], a[2], a[3]);
  *(float4*)(prep + (size_t)t * 8 + 4) = make_float4(w[0], w[1], w[2], w[3]);
}

// ---------------------------------------------------------------------------
// sample_attn2: one wave per (b,n,h), lane = channel. Per point: 2 uniform
// loads of prep data, 4 gathers, 4 FMA, 1 logit FMA, 6-step shfl reduce.
// Writes weighted as bf16 (feeds the out MFMA GEMM directly).
// ---------------------------------------------------------------------------
__global__ __launch_bounds__(256) void sample_attn2(
    const unsigned short* __restrict__ kvt, // [B*HH, S, 64] bf16
    const int* __restrict__ prep,           // [B*N*HH*20, 8]
    const float* __restrict__ qb,           // [B*N, 256]
    const float* __restrict__ pencs,        // [HH, 20, 32]
    unsigned short* __restrict__ wtd) {     // [B*N, 256] bf16
  const int grp = __builtin_amdgcn_readfirstlane(blockIdx.x * 4 + (threadIdx.x >> 6));
  const int lane = threadIdx.x & 63;
  const int h = grp & 7;
  const int bn = grp >> 3;
  const int b = bn >> 11;
  const unsigned short* kvb = kvt + (size_t)(b * HH + h) * (S_ * 64);
  const int cl = lane & 31;

  const float q = qb[(size_t)bn * 256 + h * DQK + cl] * 0.17677669529663687f;
  float qpe[20];
  {
    const float* pe = pencs + (size_t)(h * 20) * DQK + cl;
#pragma unroll
    for (int pp = 0; pp < 20; ++pp) qpe[pp] = q * pe[pp * DQK];
  }

  const int* pb = prep + (size_t)grp * 160;
  float sampled[20], logit[20];
#pragma unroll
  for (int pp = 0; pp < 20; ++pp) {
    const int4 a = *(const int4*)(pb + pp * 8);
    const float4 w = *(const float4*)(pb + pp * 8 + 4);
    const float f0 = b2f(kvb[(unsigned)(a.x * 64 + lane)]);
    const float f1 = b2f(kvb[(unsigned)(a.y * 64 + lane)]);
    const float f2 = b2f(kvb[(unsigned)(a.z * 64 + lane)]);
    const float f3 = b2f(kvb[(unsigned)(a.w * 64 + lane)]);
    const float val = f0 * w.x + f1 * w.y + f2 * w.z + f3 * w.w;
    sampled[pp] = val;
    float part = (lane < DQK) ? fmaf(q, val, qpe[pp]) : 0.f;
#pragma unroll
    for (int m = 32; m >= 1; m >>= 1) part += __shfl_xor(part, m, 64);
    logit[pp] = part;
  }

  float mx = logit[0];
#pragma unroll
  for (int pp = 1; pp < 20; ++pp) mx = fmaxf(mx, logit[pp]);
  float se = 0.f;
#pragma unroll
  for (int pp = 0; pp < 20; ++pp) {
    logit[pp] = __expf(logit[pp] - mx);
    se += logit[pp];
  }
  const float inv = 1.f / se;

  if (lane >= DQK) {
    float acc = 0.f;
#pragma unroll
    for (int pp = 0; pp < 20; ++pp) acc = fmaf(logit[pp], sampled[pp], acc);
    wtd[(size_t)bn * 256 + h * DQK + (lane - DQK)] = f2b(acc * inv);
  }
}

// ---------------------------------------------------------------------------
extern "C" void kernel_launch(void* const* d_in, const int* in_sizes, int n_in,
                              void* d_out, int out_size, void* d_ws, size_t ws_size,
                              hipStream_t stream) {
  const float* in_feats = (const float*)d_in[0];
  const float* priors   = (const float*)d_in[1];
  const float* sfeats   = (const float*)d_in[2];
  const int*   shapes   = (const int*)d_in[3];
  const int*   starts   = (const int*)d_in[4];
  const float* W_off    = (const float*)d_in[5];
  const float* b_off    = (const float*)d_in[6];
  const float* W_q      = (const float*)d_in[7];
  const float* b_q      = (const float*)d_in[8];
  const float* W_kv     = (const float*)d_in[9];
  const float* b_kv     = (const float*)d_in[10];
  const float* pencs    = (const float*)d_in[11];
  const float* W_out    = (const float*)d_in[12];
  const float* b_out    = (const float*)d_in[13];
  float* out = (float*)d_out;

  char* w = (char*)d_ws;
  unsigned short* kvt = (unsigned short*)w;           // 16*S_*64 bf16 = 44.7MB
  w += (size_t)B_ * HH * S_ * 64 * 2;
  unsigned short* sf_bf = (unsigned short*)w;         // 43648*256 bf16 = 22.3MB
  w += (size_t)B_ * S_ * 256 * 2;
  unsigned short* if_bf = (unsigned short*)w;         // 4096*256 bf16
  w += (size_t)B_ * N_ * 256 * 2;
  unsigned short* wkv_bf = (unsigned short*)w;  w += (size_t)512 * 256 * 2;
  unsigned short* wq_bf  = (unsigned short*)w;  w += (size_t)256 * 256 * 2;
  unsigned short* wout_bf = (unsigned short*)w; w += (size_t)256 * 256 * 2;
  float* offb = (float*)w;  w += (size_t)B_ * N_ * 320 * 4;
  float* qb   = (float*)w;  w += (size_t)B_ * N_ * 256 * 4;
  unsigned short* wtd_bf = (unsigned short*)w; w += (size_t)B_ * N_ * 256 * 2;
  // prep aliases sf_bf (dead after the kv GEMM): needs 655360*32B = 21MB < 22.3MB
  int* prep = (int*)sf_bf;

  const int MBN = B_ * N_;   // 4096
  const int MKV = B_ * S_;   // 43648

  cvt_f32_bf16<<<(MKV * 256 / 8 + 255) / 256, 256, 0, stream>>>(sfeats, sf_bf, MKV * 256 / 8);
  cvt_f32_bf16<<<(MBN * 256 / 8 + 255) / 256, 256, 0, stream>>>(in_feats, if_bf, MBN * 256 / 8);
  cvt_f32_bf16<<<(512 * 256 / 8 + 255) / 256, 256, 0, stream>>>(W_kv, wkv_bf, 512 * 256 / 8);
  cvt_f32_bf16<<<(256 * 256 / 8 + 255) / 256, 256, 0, stream>>>(W_q, wq_bf, 256 * 256 / 8);
  cvt_f32_bf16<<<(256 * 256 / 8 + 255) / 256, 256, 0, stream>>>(W_out, wout_bf, 256 * 256 / 8);

  // kv = sfeats @ W_kv^T + b_kv -> bf16 [B*HH, S, 64]
  gemm_mfma<1><<<dim3(512 / 128, MKV / 128), 256, 0, stream>>>(
      sf_bf, wkv_bf, b_kv, kvt, 512, 256);
  // off = in_feats @ W_off^T + b_off (f32: keeps sampling coords exact)
  gemm_f32<<<dim3(320 / 64, MBN / 64), 256, 0, stream>>>(
      in_feats, W_off, b_off, offb, MBN, 320, 256);
  // q = in_feats @ W_q^T + b_q  (bf16 MFMA, f32 out)
  gemm_mfma<0><<<dim3(256 / 128, MBN / 128), 256, 0, stream>>>(
      if_bf, wq_bf, b_q, qb, 256, 256);
  // corner addresses + weights (overwrites sf_bf — kv GEMM already done)
  prep_points<<<(MBN * HH * 20) / 256, 256, 0, stream>>>(
      offb, priors, shapes, starts, prep);
  // sampling + attention -> weighted bf16
  sample_attn2<<<(MBN * HH) / 4, 256, 0, stream>>>(
      kvt, prep, qb, pencs, wtd_bf);
  // out = weighted @ W_out^T + b_out (bf16 MFMA, f32 out)
  gemm_mfma<0><<<dim3(256 / 128, MBN / 128), 256, 0, stream>>>(
      wtd_bf, wout_bf, b_out, out, 256, 256);
}

// Round 6
// 117.295 us; speedup vs baseline: 3.0845x; 1.1924x over previous
//
#include <hip/hip_runtime.h>
#include <cstddef>

#define B_  2
#define N_  2048
#define L_  5
#define HH  8
#define P_  4
#define S_  21824
#define DQK 32

using bf16x8 = __attribute__((ext_vector_type(8))) short;
using f32x4  = __attribute__((ext_vector_type(4))) float;
using us8    = __attribute__((ext_vector_type(8))) unsigned short;

__device__ __forceinline__ unsigned short f2b(float f) {
  unsigned u = __builtin_bit_cast(unsigned, f);
  u += 0x7FFFu + ((u >> 16) & 1u);            // round-to-nearest-even
  return (unsigned short)(u >> 16);
}

__device__ __forceinline__ void gld_lds16(const void* g, void* l) {
  __builtin_amdgcn_global_load_lds(
      (const __attribute__((address_space(1))) unsigned int*)g,
      (__attribute__((address_space(3))) unsigned int*)l, 16, 0, 0);
}

// ---------------------------------------------------------------------------
// Merged f32 -> bf16 conversion for all 5 tensors. Region boundaries are
// block-aligned (5456/512/64/32/32 blocks), so no intra-block divergence.
// ---------------------------------------------------------------------------
#define C0 1396736   // sfeats   43648*256/8
#define C1 1527808   // +in_feats 4096*256/8
#define C2 1544192   // +W_kv     512*256/8
#define C3 1552384   // +W_q      256*256/8
#define C4 1560576   // +W_out    256*256/8
__global__ __launch_bounds__(256) void cvt_all(
    const float* __restrict__ s0, const float* __restrict__ s1,
    const float* __restrict__ s2, const float* __restrict__ s3,
    const float* __restrict__ s4,
    unsigned short* __restrict__ d0, unsigned short* __restrict__ d1,
    unsigned short* __restrict__ d2, unsigned short* __restrict__ d3,
    unsigned short* __restrict__ d4) {
  const int i = blockIdx.x * 256 + threadIdx.x;
  const float* src; unsigned short* dst; int off;
  if      (i < C0) { src = s0; dst = d0; off = i; }
  else if (i < C1) { src = s1; dst = d1; off = i - C0; }
  else if (i < C2) { src = s2; dst = d2; off = i - C1; }
  else if (i < C3) { src = s3; dst = d3; off = i - C2; }
  else             { src = s4; dst = d4; off = i - C3; }
  const float4 a = ((const float4*)src)[2 * off];
  const float4 b = ((const float4*)src)[2 * off + 1];
  us8 o;
  o[0] = f2b(a.x); o[1] = f2b(a.y); o[2] = f2b(a.z); o[3] = f2b(a.w);
  o[4] = f2b(b.x); o[5] = f2b(b.y); o[6] = f2b(b.z); o[7] = f2b(b.w);
  ((us8*)dst)[off] = o;
}

// ---------------------------------------------------------------------------
// bf16 MFMA GEMM: C[M,N] = A[M,K]bf16 @ W[N,K]bf16^T + bias_f32
// MODE 0: C = float*, row-major [M,N]
// MODE 1: C = ushort* (bf16), kv layout: m=(b,s), n=(h,c) ->
//         C[((b*HH+h)*S_ + s)*64 + c]
// 128x128 tile, BK=64, 4 waves (2x2). global_load_lds(16B) staging with XOR
// chunk swizzle on the GLOBAL source + swizzled ds_read (both-sides, rule 21).
// ---------------------------------------------------------------------------
template <int MODE>
__global__ __launch_bounds__(256) void gemm_mfma(
    const unsigned short* __restrict__ A,
    const unsigned short* __restrict__ Wt,
    const float* __restrict__ bias,
    void* __restrict__ Cv, int N, int K) {
  __shared__ __align__(16) unsigned short As[128 * 64];
  __shared__ __align__(16) unsigned short Bs[128 * 64];

  const int tid = threadIdx.x;
  const int lane = tid & 63;
  const int wv = tid >> 6;
  const int wr = wv >> 1, wc = wv & 1;
  const int fr = lane & 15, fq = lane >> 4;
  const int row0 = blockIdx.y * 128, col0 = blockIdx.x * 128;
  const int srow = tid >> 3;
  const int sch = tid & 7;

  f32x4 acc[4][4] = {};

  for (int k0 = 0; k0 < K; k0 += 64) {
#pragma unroll
    for (int i = 0; i < 4; ++i) {
      const int r = i * 32 + srow;
      const int ca = sch ^ (r & 7);
      gld_lds16(A + (size_t)(row0 + r) * K + k0 + ca * 8,
                As + (size_t)(i * 32 + wv * 8) * 64);
      gld_lds16(Wt + (size_t)(col0 + r) * K + k0 + ca * 8,
                Bs + (size_t)(i * 32 + wv * 8) * 64);
    }
    __syncthreads();
#pragma unroll
    for (int kk = 0; kk < 2; ++kk) {
      bf16x8 af[4], bfv[4];
#pragma unroll
      for (int i = 0; i < 4; ++i) {
        const int ar = wr * 64 + i * 16 + fr;
        const int cha = (kk * 4 + fq) ^ (ar & 7);
        af[i] = *(const bf16x8*)(As + ar * 64 + cha * 8);
        const int br = wc * 64 + i * 16 + fr;
        const int chb = (kk * 4 + fq) ^ (br & 7);
        bfv[i] = *(const bf16x8*)(Bs + br * 64 + chb * 8);
      }
#pragma unroll
      for (int i = 0; i < 4; ++i)
#pragma unroll
        for (int j = 0; j < 4; ++j)
          acc[i][j] = __builtin_amdgcn_mfma_f32_16x16x32_bf16(
              af[i], bfv[j], acc[i][j], 0, 0, 0);
    }
    __syncthreads();
  }

#pragma unroll
  for (int j = 0; j < 4; ++j) {
    const int n = col0 + wc * 64 + j * 16 + fr;
    const float bv = bias[n];
#pragma unroll
    for (int i = 0; i < 4; ++i) {
      const int mbase = row0 + wr * 64 + i * 16 + fq * 4;
#pragma unroll
      for (int r = 0; r < 4; ++r) {
        const int m = mbase + r;
        if (MODE == 0) {
          ((float*)Cv)[(size_t)m * N + n] = acc[i][j][r] + bv;
        } else {
          const int b = (m >= S_) ? 1 : 0;
          const int s = m - b * S_;
          const int h = n >> 6, c = n & 63;
          ((unsigned short*)Cv)[((size_t)(b * HH + h) * S_ + s) * 64 + c] =
              f2b(acc[i][j][r] + bv);
        }
      }
    }
  }
}

// ---------------------------------------------------------------------------
// f32 GEMM (kept for off: N=320, coords stay exact): C = A @ W^T + bias
// ---------------------------------------------------------------------------
__global__ __launch_bounds__(256) void gemm_f32(
    const float* __restrict__ A, const float* __restrict__ W,
    const float* __restrict__ bias, float* __restrict__ C,
    int M, int N, int K) {
  __shared__ float Asm[32][68];
  __shared__ float Wsm[32][68];

  const int tid = threadIdx.x;
  const int tx = tid & 15, ty = tid >> 4;
  const int row0 = blockIdx.y * 64, col0 = blockIdx.x * 64;
  const int r = tid >> 3;
  const int kq = (tid & 7) << 2;

  float acc[4][4] = {};

  for (int k0 = 0; k0 < K; k0 += 32) {
    const float4 a0 = *(const float4*)(A + (size_t)(row0 + r) * K + k0 + kq);
    const float4 a1 = *(const float4*)(A + (size_t)(row0 + r + 32) * K + k0 + kq);
    const float4 w0 = *(const float4*)(W + (size_t)(col0 + r) * K + k0 + kq);
    const float4 w1 = *(const float4*)(W + (size_t)(col0 + r + 32) * K + k0 + kq);
    __syncthreads();
    Asm[kq + 0][r] = a0.x; Asm[kq + 1][r] = a0.y; Asm[kq + 2][r] = a0.z; Asm[kq + 3][r] = a0.w;
    Asm[kq + 0][r + 32] = a1.x; Asm[kq + 1][r + 32] = a1.y; Asm[kq + 2][r + 32] = a1.z; Asm[kq + 3][r + 32] = a1.w;
    Wsm[kq + 0][r] = w0.x; Wsm[kq + 1][r] = w0.y; Wsm[kq + 2][r] = w0.z; Wsm[kq + 3][r] = w0.w;
    Wsm[kq + 0][r + 32] = w1.x; Wsm[kq + 1][r + 32] = w1.y; Wsm[kq + 2][r + 32] = w1.z; Wsm[kq + 3][r + 32] = w1.w;
    __syncthreads();
#pragma unroll
    for (int kk = 0; kk < 32; ++kk) {
      const float4 av = *(const float4*)&Asm[kk][ty << 2];
      const float4 bv = *(const float4*)&Wsm[kk][tx << 2];
      const float* ap = (const float*)&av;
      const float* bp = (const float*)&bv;
#pragma unroll
      for (int i = 0; i < 4; ++i)
#pragma unroll
        for (int j = 0; j < 4; ++j) acc[i][j] += ap[i] * bp[j];
    }
  }

  const float4 bb = *(const float4*)(bias + col0 + (tx << 2));
  const float* bbp = (const float*)&bb;
#pragma unroll
  for (int i = 0; i < 4; ++i) {
    const int m = row0 + (ty << 2) + i;
    float4 o;
    o.x = acc[i][0] + bbp[0];
    o.y = acc[i][1] + bbp[1];
    o.z = acc[i][2] + bbp[2];
    o.w = acc[i][3] + bbp[3];
    *(float4*)(C + (size_t)m * N + col0 + (tx << 2)) = o;
  }
}

// ---------------------------------------------------------------------------
// sample_attn3: one wave per (b,n,h). Lane j=lane&31 owns CHANNEL PAIR
// (2j, 2j+1); half=lane>>5 processes even/odd points concurrently.
// Phase A: lanes 0-19 compute 20 points' corner addrs/weights into LDS.
// Main loop: 10 point-pair steps, dword gathers, packed bilinear, 5-step
// 32-wide reduce. Softmax halves exchanged via shfl_xor(32).
// ---------------------------------------------------------------------------
__global__ __launch_bounds__(256) void sample_attn3(
    const unsigned short* __restrict__ kvt, // [B*HH, S, 64] bf16
    const float* __restrict__ offb,         // [B*N, 320]
    const float* __restrict__ qb,           // [B*N, 256]
    const float* __restrict__ priors,       // [B, N, L, 2]
    const int* __restrict__ shapes,         // [L, 2] (H, W)
    const int* __restrict__ starts,         // [L]
    const float* __restrict__ pencs,        // [HH, 20, 32]
    unsigned short* __restrict__ wtd) {     // [B*N, 256] bf16
  __shared__ __align__(16) int pbuf[4][20][8];
  const int wv = threadIdx.x >> 6;
  const int grp = blockIdx.x * 4 + wv;
  const int lane = threadIdx.x & 63;
  const int j = lane & 31;
  const int half = lane >> 5;
  const int h = grp & 7;
  const int bn = grp >> 3;
  const int b = bn >> 11;

  // Phase A: per-point coordinate math (lanes 0..19), results to LDS
  if (lane < 20) {
    const int pp = lane;
    const int l = pp >> 2;
    const float2 oxy = *(const float2*)(offb + (size_t)bn * 320 + h * 40 + pp * 2);
    const float2 pxy = *(const float2*)(priors + ((size_t)bn * 5 + l) * 2);
    const int Wd = shapes[l * 2 + 1];
    const int Hd = shapes[l * 2 + 0];
    const int st = starts[l];
    const float Wf = (float)Wd, Hf = (float)Hd;
    const float x = (pxy.x + oxy.x / Wf) * Wf - 0.5f;
    const float y = (pxy.y + oxy.y / Hf) * Hf - 0.5f;
    const float x0f = floorf(x), y0f = floorf(y);
    const float fx = x - x0f, fy = y - y0f;
    const int xi = (int)x0f, yi = (int)y0f;
    int a[4]; float w[4];
#pragma unroll
    for (int dy = 0; dy < 2; ++dy)
#pragma unroll
      for (int dx = 0; dx < 2; ++dx) {
        const int xc = xi + dx, yc = yi + dy;
        const bool valid = (xc >= 0) & (xc < Wd) & (yc >= 0) & (yc < Hd);
        const float wt = (dx ? fx : 1.f - fx) * (dy ? fy : 1.f - fy);
        const int xcc = min(max(xc, 0), Wd - 1);
        const int ycc = min(max(yc, 0), Hd - 1);
        a[dy * 2 + dx] = st + ycc * Wd + xcc;
        w[dy * 2 + dx] = valid ? wt : 0.f;
      }
    *(int4*)&pbuf[wv][pp][0] = make_int4(a[0], a[1], a[2], a[3]);
    *(float4*)&pbuf[wv][pp][4] = make_float4(w[0], w[1], w[2], w[3]);
  }

  // q (channel pair) + precomputed q·penc per point of my parity
  const int jc = j & 15;   // clamp so V-lanes load in-bounds (result unused)
  float2 q2 = *(const float2*)(qb + (size_t)bn * 256 + h * DQK + 2 * jc);
  q2.x *= 0.17677669529663687f;
  q2.y *= 0.17677669529663687f;
  float qpe[10];
#pragma unroll
  for (int i = 0; i < 10; ++i) {
    const float2 pe = *(const float2*)(
        pencs + ((size_t)h * 20 + 2 * i + half) * DQK + 2 * jc);
    qpe[i] = q2.x * pe.x + q2.y * pe.y;
  }

  const unsigned* kvd = (const unsigned*)(kvt + (size_t)(b * HH + h) * (S_ * 64));
  float2 sam[10];
  float lg[10];
#pragma unroll
  for (int i = 0; i < 10; ++i) {
    const int pt = 2 * i + half;
    const int4 a = *(const int4*)&pbuf[wv][pt][0];
    const float4 wt = *(const float4*)&pbuf[wv][pt][4];
    const unsigned g0 = kvd[(unsigned)a.x * 32u + j];
    const unsigned g1 = kvd[(unsigned)a.y * 32u + j];
    const unsigned g2 = kvd[(unsigned)a.z * 32u + j];
    const unsigned g3 = kvd[(unsigned)a.w * 32u + j];
    const float lo0 = __builtin_bit_cast(float, g0 << 16);
    const float hi0 = __builtin_bit_cast(float, g0 & 0xFFFF0000u);
    const float lo1 = __builtin_bit_cast(float, g1 << 16);
    const float hi1 = __builtin_bit_cast(float, g1 & 0xFFFF0000u);
    const float lo2 = __builtin_bit_cast(float, g2 << 16);
    const float hi2 = __builtin_bit_cast(float, g2 & 0xFFFF0000u);
    const float lo3 = __builtin_bit_cast(float, g3 << 16);
    const float hi3 = __builtin_bit_cast(float, g3 & 0xFFFF0000u);
    float vx = wt.x * lo0;  vx = fmaf(wt.y, lo1, vx);
    vx = fmaf(wt.z, lo2, vx); vx = fmaf(wt.w, lo3, vx);
    float vy = wt.x * hi0;  vy = fmaf(wt.y, hi1, vy);
    vy = fmaf(wt.z, hi2, vy); vy = fmaf(wt.w, hi3, vy);
    sam[i].x = vx; sam[i].y = vy;
    float part = (j < 16) ? fmaf(q2.x, vx, fmaf(q2.y, vy, qpe[i])) : 0.f;
#pragma unroll
    for (int m = 16; m >= 1; m >>= 1) part += __shfl_xor(part, m, 64);
    lg[i] = part;   // all 32 lanes of this half hold logit(pt)
  }

  // global softmax across both halves
  float mx = lg[0];
#pragma unroll
  for (int i = 1; i < 10; ++i) mx = fmaxf(mx, lg[i]);
  mx = fmaxf(mx, __shfl_xor(mx, 32, 64));
  float se = 0.f;
#pragma unroll
  for (int i = 0; i < 10; ++i) {
    lg[i] = __expf(lg[i] - mx);
    se += lg[i];
  }
  se += __shfl_xor(se, 32, 64);
  const float inv = 1.f / se;

  // weighted V accumulation (channel pair), combine parities
  float ax = 0.f, ay = 0.f;
#pragma unroll
  for (int i = 0; i < 10; ++i) {
    ax = fmaf(lg[i], sam[i].x, ax);
    ay = fmaf(lg[i], sam[i].y, ay);
  }
  ax += __shfl_xor(ax, 32, 64);
  ay += __shfl_xor(ay, 32, 64);

  if (half == 0 && j >= 16) {
    const unsigned u = (unsigned)f2b(ax * inv) | ((unsigned)f2b(ay * inv) << 16);
    ((unsigned*)wtd)[(size_t)bn * 128 + h * 16 + (j - 16)] = u;
  }
}

// ---------------------------------------------------------------------------
extern "C" void kernel_launch(void* const* d_in, const int* in_sizes, int n_in,
                              void* d_out, int out_size, void* d_ws, size_t ws_size,
                              hipStream_t stream) {
  const float* in_feats = (const float*)d_in[0];
  const float* priors   = (const float*)d_in[1];
  const float* sfeats   = (const float*)d_in[2];
  const int*   shapes   = (const int*)d_in[3];
  const int*   starts   = (const int*)d_in[4];
  const float* W_off    = (const float*)d_in[5];
  const float* b_off    = (const float*)d_in[6];
  const float* W_q      = (const float*)d_in[7];
  const float* b_q      = (const float*)d_in[8];
  const float* W_kv     = (const float*)d_in[9];
  const float* b_kv     = (const float*)d_in[10];
  const float* pencs    = (const float*)d_in[11];
  const float* W_out    = (const float*)d_in[12];
  const float* b_out    = (const float*)d_in[13];
  float* out = (float*)d_out;

  char* w = (char*)d_ws;
  unsigned short* kvt = (unsigned short*)w;           // 16*S_*64 bf16 = 44.7MB
  w += (size_t)B_ * HH * S_ * 64 * 2;
  unsigned short* sf_bf = (unsigned short*)w;         // 43648*256 bf16 = 22.3MB
  w += (size_t)B_ * S_ * 256 * 2;
  unsigned short* if_bf = (unsigned short*)w;         // 4096*256 bf16
  w += (size_t)B_ * N_ * 256 * 2;
  unsigned short* wkv_bf = (unsigned short*)w;  w += (size_t)512 * 256 * 2;
  unsigned short* wq_bf  = (unsigned short*)w;  w += (size_t)256 * 256 * 2;
  unsigned short* wout_bf = (unsigned short*)w; w += (size_t)256 * 256 * 2;
  float* offb = (float*)w;  w += (size_t)B_ * N_ * 320 * 4;
  float* qb   = (float*)w;  w += (size_t)B_ * N_ * 256 * 4;
  unsigned short* wtd_bf = (unsigned short*)w; w += (size_t)B_ * N_ * 256 * 2;

  const int MBN = B_ * N_;   // 4096
  const int MKV = B_ * S_;   // 43648

  // all f32->bf16 conversions in one launch (6096 blocks)
  cvt_all<<<C4 / 256, 256, 0, stream>>>(
      sfeats, in_feats, W_kv, W_q, W_out,
      sf_bf, if_bf, wkv_bf, wq_bf, wout_bf);

  // kv = sfeats @ W_kv^T + b_kv -> bf16 [B*HH, S, 64]
  gemm_mfma<1><<<dim3(512 / 128, MKV / 128), 256, 0, stream>>>(
      sf_bf, wkv_bf, b_kv, kvt, 512, 256);
  // off = in_feats @ W_off^T + b_off (f32: keeps sampling coords exact)
  gemm_f32<<<dim3(320 / 64, MBN / 64), 256, 0, stream>>>(
      in_feats, W_off, b_off, offb, MBN, 320, 256);
  // q = in_feats @ W_q^T + b_q  (bf16 MFMA, f32 out)
  gemm_mfma<0><<<dim3(256 / 128, MBN / 128), 256, 0, stream>>>(
      if_bf, wq_bf, b_q, qb, 256, 256);
  // fused coordinate prep + sampling + attention -> weighted bf16
  sample_attn3<<<(MBN * HH) / 4, 256, 0, stream>>>(
      kvt, offb, qb, priors, shapes, starts, pencs, wtd_bf);
  // out = weighted @ W_out^T + b_out (bf16 MFMA, f32 out)
  gemm_mfma<0><<<dim3(256 / 128, MBN / 128), 256, 0, stream>>>(
      wtd_bf, wout_bf, b_out, out, 256, 256);
}

// Round 7
// 99.911 us; speedup vs baseline: 3.6212x; 1.1740x over previous
//
#include <hip/hip_runtime.h>
#include <cstddef>

#define B_  2
#define N_  2048
#define L_  5
#define HH  8
#define P_  4
#define S_  21824
#define DQK 32

using bf16x8 = __attribute__((ext_vector_type(8))) short;
using f32x4  = __attribute__((ext_vector_type(4))) float;
using us8    = __attribute__((ext_vector_type(8))) unsigned short;

__device__ __forceinline__ unsigned short f2b(float f) {
  unsigned u = __builtin_bit_cast(unsigned, f);
  u += 0x7FFFu + ((u >> 16) & 1u);            // round-to-nearest-even
  return (unsigned short)(u >> 16);
}
__device__ __forceinline__ float b2f(unsigned short h) {
  return __builtin_bit_cast(float, ((unsigned)h) << 16);
}

__device__ __forceinline__ void gld_lds16(const void* g, void* l) {
  __builtin_amdgcn_global_load_lds(
      (const __attribute__((address_space(1))) unsigned int*)g,
      (__attribute__((address_space(3))) unsigned int*)l, 16, 0, 0);
}

// DPP-based add: v += permuted(v). VALU pipe, no LDS round-trip.
template <int CTRL>
__device__ __forceinline__ float dppadd(float v) {
  const int x = __builtin_bit_cast(int, v);
  return v + __builtin_bit_cast(float,
      __builtin_amdgcn_update_dpp(x, x, CTRL, 0xF, 0xF, false));
}

// ---------------------------------------------------------------------------
// Merged f32 -> bf16 conversions (plain / lo-residual / zero-padded W_off).
// Region boundaries all divisible by 256 units -> block-uniform branches.
// ---------------------------------------------------------------------------
#define E0 1396736   // sfeats -> sf_bf           (43648*256/8)
#define E1 1527808   // + in_feats -> if_hi        (4096*256/8)
#define E2 1658880   // + in_feats -> if_lo        (4096*256/8)
#define E3 1675264   // + W_kv -> wkv_bf           (512*256/8)
#define E4 1683456   // + W_q  -> wq_bf            (256*256/8)
#define E5 1691648   // + W_out -> wout_bf         (256*256/8)
#define E6 1703936   // + W_off(pad384) -> woff_hi (384*256/8)
#define E7 1716224   // + W_off(pad384) -> woff_lo (384*256/8)

__device__ __forceinline__ void cvt8_plain(const float* s, unsigned short* d, int u) {
  const float4 a = ((const float4*)s)[2 * u];
  const float4 b = ((const float4*)s)[2 * u + 1];
  us8 o;
  o[0] = f2b(a.x); o[1] = f2b(a.y); o[2] = f2b(a.z); o[3] = f2b(a.w);
  o[4] = f2b(b.x); o[5] = f2b(b.y); o[6] = f2b(b.z); o[7] = f2b(b.w);
  ((us8*)d)[u] = o;
}
__device__ __forceinline__ unsigned short f2b_lo(float x) {
  return f2b(x - b2f(f2b(x)));
}
__device__ __forceinline__ void cvt8_lo(const float* s, unsigned short* d, int u) {
  const float4 a = ((const float4*)s)[2 * u];
  const float4 b = ((const float4*)s)[2 * u + 1];
  us8 o;
  o[0] = f2b_lo(a.x); o[1] = f2b_lo(a.y); o[2] = f2b_lo(a.z); o[3] = f2b_lo(a.w);
  o[4] = f2b_lo(b.x); o[5] = f2b_lo(b.y); o[6] = f2b_lo(b.z); o[7] = f2b_lo(b.w);
  ((us8*)d)[u] = o;
}

__global__ __launch_bounds__(256) void cvt_all(
    const float* __restrict__ sfeats, const float* __restrict__ in_feats,
    const float* __restrict__ W_kv, const float* __restrict__ W_q,
    const float* __restrict__ W_out, const float* __restrict__ W_off,
    unsigned short* __restrict__ sf_bf, unsigned short* __restrict__ if_hi,
    unsigned short* __restrict__ if_lo, unsigned short* __restrict__ wkv_bf,
    unsigned short* __restrict__ wq_bf, unsigned short* __restrict__ wout_bf,
    unsigned short* __restrict__ woff_hi, unsigned short* __restrict__ woff_lo) {
  const int i = blockIdx.x * 256 + threadIdx.x;
  if      (i < E0) cvt8_plain(sfeats, sf_bf, i);
  else if (i < E1) cvt8_plain(in_feats, if_hi, i - E0);
  else if (i < E2) cvt8_lo(in_feats, if_lo, i - E1);
  else if (i < E3) cvt8_plain(W_kv, wkv_bf, i - E2);
  else if (i < E4) cvt8_plain(W_q, wq_bf, i - E3);
  else if (i < E5) cvt8_plain(W_out, wout_bf, i - E4);
  else if (i < E6) {
    const int u = i - E5;
    if ((u >> 5) < 320) cvt8_plain(W_off, woff_hi, u);
    else ((us8*)woff_hi)[u] = (us8)0;
  } else {
    const int u = i - E6;
    if ((u >> 5) < 320) cvt8_lo(W_off, woff_lo, u);
    else ((us8*)woff_lo)[u] = (us8)0;
  }
}

// ---------------------------------------------------------------------------
// Shared MFMA tile body (128x128, BK=64, 4 waves 2x2). Stages via
// global_load_lds(16B), XOR chunk swizzle on global source + swizzled ds_read.
// ---------------------------------------------------------------------------
__device__ __forceinline__ void mfma_tile_k256(
    const unsigned short* __restrict__ Ap, const unsigned short* __restrict__ Wp,
    unsigned short* As, unsigned short* Bs,
    int row0, int col0, int wv, int wr, int wc, int fr, int fq,
    int srow, int sch, f32x4 (&acc)[4][4]) {
  for (int k0 = 0; k0 < 256; k0 += 64) {
#pragma unroll
    for (int i = 0; i < 4; ++i) {
      const int r = i * 32 + srow;
      const int ca = sch ^ (r & 7);
      gld_lds16(Ap + (size_t)(row0 + r) * 256 + k0 + ca * 8,
                As + (size_t)(i * 32 + wv * 8) * 64);
      gld_lds16(Wp + (size_t)(col0 + r) * 256 + k0 + ca * 8,
                Bs + (size_t)(i * 32 + wv * 8) * 64);
    }
    __syncthreads();
#pragma unroll
    for (int kk = 0; kk < 2; ++kk) {
      bf16x8 af[4], bfv[4];
#pragma unroll
      for (int i = 0; i < 4; ++i) {
        const int ar = wr * 64 + i * 16 + fr;
        const int cha = (kk * 4 + fq) ^ (ar & 7);
        af[i] = *(const bf16x8*)(As + ar * 64 + cha * 8);
        const int br = wc * 64 + i * 16 + fr;
        const int chb = (kk * 4 + fq) ^ (br & 7);
        bfv[i] = *(const bf16x8*)(Bs + br * 64 + chb * 8);
      }
#pragma unroll
      for (int i = 0; i < 4; ++i)
#pragma unroll
        for (int j = 0; j < 4; ++j)
          acc[i][j] = __builtin_amdgcn_mfma_f32_16x16x32_bf16(
              af[i], bfv[j], acc[i][j], 0, 0, 0);
    }
    __syncthreads();
  }
}

// ---------------------------------------------------------------------------
// Ubergemm: one launch for kv (MODE1), off (bf16x3, 3 K-segments) and q.
// blocks [0,1364): kv | [1364,1460): off | [1460,1524): q
// ---------------------------------------------------------------------------
__global__ __launch_bounds__(256) void ubergemm(
    const unsigned short* __restrict__ sf_bf,
    const unsigned short* __restrict__ wkv_bf,
    const unsigned short* __restrict__ if_hi,
    const unsigned short* __restrict__ if_lo,
    const unsigned short* __restrict__ woff_hi,
    const unsigned short* __restrict__ woff_lo,
    const unsigned short* __restrict__ wq_bf,
    const float* __restrict__ b_kv, const float* __restrict__ b_off,
    const float* __restrict__ b_q,
    unsigned short* __restrict__ kvt, float* __restrict__ offb,
    float* __restrict__ qb) {
  __shared__ __align__(16) unsigned short As[128 * 64];
  __shared__ __align__(16) unsigned short Bs[128 * 64];

  const int tid = threadIdx.x;
  const int lane = tid & 63;
  const int wv = tid >> 6;
  const int wr = wv >> 1, wc = wv & 1;
  const int fr = lane & 15, fq = lane >> 4;
  const int srow = tid >> 3;
  const int sch = tid & 7;
  const int bx = blockIdx.x;

  int mode, nseg, row0, col0, ldc = 0, nbias = 0;
  const unsigned short *A0, *W0, *A1 = nullptr, *W1 = nullptr,
                       *A2 = nullptr, *W2 = nullptr;
  const float* bias;
  float* Cf = nullptr;
  if (bx < 1364) {
    mode = 1; nseg = 1; A0 = sf_bf; W0 = wkv_bf; bias = b_kv;
    col0 = (bx & 3) * 128; row0 = (bx >> 2) * 128;
  } else if (bx < 1460) {
    const int t = bx - 1364;
    mode = 0; nseg = 3;
    A0 = if_hi; W0 = woff_hi; A1 = if_hi; W1 = woff_lo; A2 = if_lo; W2 = woff_hi;
    bias = b_off; Cf = offb; ldc = 384; nbias = 320;
    col0 = (t % 3) * 128; row0 = (t / 3) * 128;
  } else {
    const int t = bx - 1460;
    mode = 0; nseg = 1; A0 = if_hi; W0 = wq_bf; bias = b_q;
    Cf = qb; ldc = 256; nbias = 256;
    col0 = (t & 1) * 128; row0 = (t >> 1) * 128;
  }

  f32x4 acc[4][4] = {};
  for (int s = 0; s < nseg; ++s) {
    const unsigned short* Ap = (s == 0) ? A0 : (s == 1) ? A1 : A2;
    const unsigned short* Wp = (s == 0) ? W0 : (s == 1) ? W1 : W2;
    mfma_tile_k256(Ap, Wp, As, Bs, row0, col0, wv, wr, wc, fr, fq, srow, sch, acc);
  }

#pragma unroll
  for (int j = 0; j < 4; ++j) {
    const int n = col0 + wc * 64 + j * 16 + fr;
    const float bv = (mode == 1) ? bias[n] : ((n < nbias) ? bias[n] : 0.f);
#pragma unroll
    for (int i = 0; i < 4; ++i) {
      const int mbase = row0 + wr * 64 + i * 16 + fq * 4;
#pragma unroll
      for (int r = 0; r < 4; ++r) {
        const int m = mbase + r;
        if (mode == 1) {
          const int b = (m >= S_) ? 1 : 0;
          const int s = m - b * S_;
          const int h = n >> 6, c = n & 63;
          kvt[((size_t)(b * HH + h) * S_ + s) * 64 + c] = f2b(acc[i][j][r] + bv);
        } else {
          Cf[(size_t)m * ldc + n] = acc[i][j][r] + bv;
        }
      }
    }
  }
}

// ---------------------------------------------------------------------------
// out-projection GEMM (separate: depends on sampler): bf16 MFMA, f32 out.
// ---------------------------------------------------------------------------
__global__ __launch_bounds__(256) void gemm_out(
    const unsigned short* __restrict__ A, const unsigned short* __restrict__ Wt,
    const float* __restrict__ bias, float* __restrict__ C) {
  __shared__ __align__(16) unsigned short As[128 * 64];
  __shared__ __align__(16) unsigned short Bs[128 * 64];
  const int tid = threadIdx.x;
  const int lane = tid & 63;
  const int wv = tid >> 6;
  const int wr = wv >> 1, wc = wv & 1;
  const int fr = lane & 15, fq = lane >> 4;
  const int row0 = blockIdx.y * 128, col0 = blockIdx.x * 128;
  const int srow = tid >> 3, sch = tid & 7;
  f32x4 acc[4][4] = {};
  mfma_tile_k256(A, Wt, As, Bs, row0, col0, wv, wr, wc, fr, fq, srow, sch, acc);
#pragma unroll
  for (int j = 0; j < 4; ++j) {
    const int n = col0 + wc * 64 + j * 16 + fr;
    const float bv = bias[n];
#pragma unroll
    for (int i = 0; i < 4; ++i) {
      const int mbase = row0 + wr * 64 + i * 16 + fq * 4;
#pragma unroll
      for (int r = 0; r < 4; ++r)
        C[(size_t)(mbase + r) * 256 + n] = acc[i][j][r] + bv;
    }
  }
}

// ---------------------------------------------------------------------------
// sample_attn4: XCD-partitioned slices; DPP reduce; 1-deep gather prefetch.
// Block beta: XCD x=beta&7 handles slices {2x, 2x+1} (5.6MB < fits L2-ish).
// Wave = one (b,n,h) query-head; lane j=lane&31 owns channel pair; halves
// process even/odd points.
// ---------------------------------------------------------------------------
__global__ __launch_bounds__(256) void sample_attn4(
    const unsigned short* __restrict__ kvt, // [B*HH, S, 64] bf16
    const float* __restrict__ offb,         // [B*N, 384]
    const float* __restrict__ qb,           // [B*N, 256]
    const float* __restrict__ priors,       // [B, N, L, 2]
    const int* __restrict__ shapes,         // [L, 2] (H, W)
    const int* __restrict__ starts,         // [L]
    const float* __restrict__ pencs,        // [HH, 20, 32]
    unsigned short* __restrict__ wtd) {     // [B*N, 256] bf16
  __shared__ __align__(16) int pbuf[4][20][8];
  const int wv = threadIdx.x >> 6;
  const int lane = threadIdx.x & 63;
  const int beta = blockIdx.x;
  const int sig = (beta & 7) * 2 + ((beta >> 3) & 1);  // slice 0..15
  const int chunk = beta >> 4;                          // 0..511
  const int h = sig & 7;
  const int b = sig >> 3;
  const int bn = b * N_ + chunk * 4 + wv;
  const int j = lane & 31;
  const int half = lane >> 5;

  // Phase A: per-point coordinate math (lanes 0..19) -> LDS (addr prescaled x32)
  if (lane < 20) {
    const int pp = lane;
    const int l = pp >> 2;
    const float2 oxy = *(const float2*)(offb + (size_t)bn * 384 + h * 40 + pp * 2);
    const float2 pxy = *(const float2*)(priors + ((size_t)bn * 5 + l) * 2);
    const int Wd = shapes[l * 2 + 1];
    const int Hd = shapes[l * 2 + 0];
    const int st = starts[l];
    const float Wf = (float)Wd, Hf = (float)Hd;
    const float x = (pxy.x + oxy.x / Wf) * Wf - 0.5f;
    const float y = (pxy.y + oxy.y / Hf) * Hf - 0.5f;
    const float x0f = floorf(x), y0f = floorf(y);
    const float fx = x - x0f, fy = y - y0f;
    const int xi = (int)x0f, yi = (int)y0f;
    int a[4]; float w[4];
#pragma unroll
    for (int dy = 0; dy < 2; ++dy)
#pragma unroll
      for (int dx = 0; dx < 2; ++dx) {
        const int xc = xi + dx, yc = yi + dy;
        const bool valid = (xc >= 0) & (xc < Wd) & (yc >= 0) & (yc < Hd);
        const float wt = (dx ? fx : 1.f - fx) * (dy ? fy : 1.f - fy);
        const int xcc = min(max(xc, 0), Wd - 1);
        const int ycc = min(max(yc, 0), Hd - 1);
        a[dy * 2 + dx] = (st + ycc * Wd + xcc) * 32;
        w[dy * 2 + dx] = valid ? wt : 0.f;
      }
    *(int4*)&pbuf[wv][pp][0] = make_int4(a[0], a[1], a[2], a[3]);
    *(float4*)&pbuf[wv][pp][4] = make_float4(w[0], w[1], w[2], w[3]);
  }

  // q channel pair + q·penc per point of my parity
  const int jc = j & 15;
  float2 q2 = *(const float2*)(qb + (size_t)bn * 256 + h * DQK + 2 * jc);
  q2.x *= 0.17677669529663687f;
  q2.y *= 0.17677669529663687f;
  float qpe[10];
#pragma unroll
  for (int i = 0; i < 10; ++i) {
    const float2 pe = *(const float2*)(
        pencs + ((size_t)h * 20 + 2 * i + half) * DQK + 2 * jc);
    qpe[i] = q2.x * pe.x + q2.y * pe.y;
  }

  const unsigned* kvd = (const unsigned*)(kvt + (size_t)(b * HH + h) * (S_ * 64));
  int4 aa[2]; float4 ww[2]; unsigned g[2][4];
  aa[0] = *(const int4*)&pbuf[wv][half][0];
  ww[0] = *(const float4*)&pbuf[wv][half][4];
  g[0][0] = kvd[(unsigned)aa[0].x + j];
  g[0][1] = kvd[(unsigned)aa[0].y + j];
  g[0][2] = kvd[(unsigned)aa[0].z + j];
  g[0][3] = kvd[(unsigned)aa[0].w + j];

  float2 sam[10];
  float lg[10];
#pragma unroll
  for (int i = 0; i < 10; ++i) {
    const int cur = i & 1, nxt = cur ^ 1;
    if (i < 9) {   // prefetch next point-pair's gathers
      aa[nxt] = *(const int4*)&pbuf[wv][2 * (i + 1) + half][0];
      ww[nxt] = *(const float4*)&pbuf[wv][2 * (i + 1) + half][4];
      g[nxt][0] = kvd[(unsigned)aa[nxt].x + j];
      g[nxt][1] = kvd[(unsigned)aa[nxt].y + j];
      g[nxt][2] = kvd[(unsigned)aa[nxt].z + j];
      g[nxt][3] = kvd[(unsigned)aa[nxt].w + j];
    }
    const float4 wt = ww[cur];
    const unsigned g0 = g[cur][0], g1 = g[cur][1], g2 = g[cur][2], g3 = g[cur][3];
    const float lo0 = __builtin_bit_cast(float, g0 << 16);
    const float hi0 = __builtin_bit_cast(float, g0 & 0xFFFF0000u);
    const float lo1 = __builtin_bit_cast(float, g1 << 16);
    const float hi1 = __builtin_bit_cast(float, g1 & 0xFFFF0000u);
    const float lo2 = __builtin_bit_cast(float, g2 << 16);
    const float hi2 = __builtin_bit_cast(float, g2 & 0xFFFF0000u);
    const float lo3 = __builtin_bit_cast(float, g3 << 16);
    const float hi3 = __builtin_bit_cast(float, g3 & 0xFFFF0000u);
    float vx = wt.x * lo0;  vx = fmaf(wt.y, lo1, vx);
    vx = fmaf(wt.z, lo2, vx); vx = fmaf(wt.w, lo3, vx);
    float vy = wt.x * hi0;  vy = fmaf(wt.y, hi1, vy);
    vy = fmaf(wt.z, hi2, vy); vy = fmaf(wt.w, hi3, vy);
    sam[i].x = vx; sam[i].y = vy;
    // logit partial on K lanes (j<16); DPP row16 reduce + one cross shfl
    float part = (j < 16) ? fmaf(q2.x, vx, fmaf(q2.y, vy, qpe[i])) : 0.f;
    part = dppadd<0xB1>(part);    // quad_perm [1,0,3,2]  (xor 1)
    part = dppadd<0x4E>(part);    // quad_perm [2,3,0,1]  (xor 2)
    part = dppadd<0x124>(part);   // row_ror:4
    part = dppadd<0x128>(part);   // row_ror:8 -> full row16 sum
    lg[i] = part + __shfl_xor(part, 16, 64);   // spread to V-lane rows
  }

  // softmax across both halves
  float mx = lg[0];
#pragma unroll
  for (int i = 1; i < 10; ++i) mx = fmaxf(mx, lg[i]);
  mx = fmaxf(mx, __shfl_xor(mx, 32, 64));
  float se = 0.f;
#pragma unroll
  for (int i = 0; i < 10; ++i) {
    lg[i] = __expf(lg[i] - mx);
    se += lg[i];
  }
  se += __shfl_xor(se, 32, 64);
  const float inv = 1.f / se;

  float ax = 0.f, ay = 0.f;
#pragma unroll
  for (int i = 0; i < 10; ++i) {
    ax = fmaf(lg[i], sam[i].x, ax);
    ay = fmaf(lg[i], sam[i].y, ay);
  }
  ax += __shfl_xor(ax, 32, 64);
  ay += __shfl_xor(ay, 32, 64);

  if (half == 0 && j >= 16) {
    const unsigned u = (unsigned)f2b(ax * inv) | ((unsigned)f2b(ay * inv) << 16);
    ((unsigned*)wtd)[(size_t)bn * 128 + h * 16 + (j - 16)] = u;
  }
}

// ---------------------------------------------------------------------------
extern "C" void kernel_launch(void* const* d_in, const int* in_sizes, int n_in,
                              void* d_out, int out_size, void* d_ws, size_t ws_size,
                              hipStream_t stream) {
  const float* in_feats = (const float*)d_in[0];
  const float* priors   = (const float*)d_in[1];
  const float* sfeats   = (const float*)d_in[2];
  const int*   shapes   = (const int*)d_in[3];
  const int*   starts   = (const int*)d_in[4];
  const float* W_off    = (const float*)d_in[5];
  const float* b_off    = (const float*)d_in[6];
  const float* W_q      = (const float*)d_in[7];
  const float* b_q      = (const float*)d_in[8];
  const float* W_kv     = (const float*)d_in[9];
  const float* b_kv     = (const float*)d_in[10];
  const float* pencs    = (const float*)d_in[11];
  const float* W_out    = (const float*)d_in[12];
  const float* b_out    = (const float*)d_in[13];
  float* out = (float*)d_out;

  char* w = (char*)d_ws;
  unsigned short* kvt = (unsigned short*)w;            // 44.7 MB
  w += (size_t)B_ * HH * S_ * 64 * 2;
  unsigned short* sf_bf = (unsigned short*)w;          // 22.3 MB
  w += (size_t)B_ * S_ * 256 * 2;
  unsigned short* if_hi = (unsigned short*)w; w += (size_t)4096 * 256 * 2;
  unsigned short* if_lo = (unsigned short*)w; w += (size_t)4096 * 256 * 2;
  unsigned short* wkv_bf = (unsigned short*)w;  w += (size_t)512 * 256 * 2;
  unsigned short* wq_bf  = (unsigned short*)w;  w += (size_t)256 * 256 * 2;
  unsigned short* wout_bf = (unsigned short*)w; w += (size_t)256 * 256 * 2;
  unsigned short* woff_hi = (unsigned short*)w; w += (size_t)384 * 256 * 2;
  unsigned short* woff_lo = (unsigned short*)w; w += (size_t)384 * 256 * 2;
  float* offb = (float*)w;  w += (size_t)4096 * 384 * 4;
  float* qb   = (float*)w;  w += (size_t)4096 * 256 * 4;
  unsigned short* wtd_bf = (unsigned short*)w; w += (size_t)4096 * 256 * 2;

  // 1) all conversions (6704 blocks)
  cvt_all<<<E7 / 256, 256, 0, stream>>>(
      sfeats, in_feats, W_kv, W_q, W_out, W_off,
      sf_bf, if_hi, if_lo, wkv_bf, wq_bf, wout_bf, woff_hi, woff_lo);

  // 2) kv + off + q in one launch (1364 + 96 + 64 = 1524 blocks)
  ubergemm<<<1524, 256, 0, stream>>>(
      sf_bf, wkv_bf, if_hi, if_lo, woff_hi, woff_lo, wq_bf,
      b_kv, b_off, b_q, kvt, offb, qb);

  // 3) fused prep + sampling + attention (XCD-partitioned slices)
  sample_attn4<<<(B_ * N_ * HH) / 4, 256, 0, stream>>>(
      kvt, offb, qb, priors, shapes, starts, pencs, wtd_bf);

  // 4) out = weighted @ W_out^T + b_out
  gemm_out<<<dim3(2, 32), 256, 0, stream>>>(wtd_bf, wout_bf, b_out, out);
}